// Round 1
// baseline (1143.617 us; speedup 1.0000x reference)
//
#include <hip/hip_runtime.h>

// MinHashSketch: sketch[512,128] = segment_min(x[500000,256] @ H[128,256]^T), empty -> 0
// Inputs: d_in[0]=x fp32, d_in[1]=batch int64-or-int32 (sorted), d_in[2]=num_segments, d_in[3]=H fp32

#define M_NODES 500000
#define KDIM    256
#define NHASH   128
#define NSEG    512

#define BM 256            // nodes per block
#define BK 16             // k-chunk
#define TN 8              // nodes per thread
#define TH 16             // hashes per thread (two groups of 8, split by 64)

#define XS_STRIDE 260     // 256 + 4 (keeps float4 alignment, breaks write conflicts)
#define HS_STRIDE 132     // 128 + 4

// Order-preserving float->uint encoding: uint-min == float-min
__device__ __forceinline__ unsigned int enc_f(float f) {
    unsigned int b = __float_as_uint(f);
    return (b & 0x80000000u) ? ~b : (b | 0x80000000u);
}

__global__ __launch_bounds__(256, 2)
void minhash_main(const float* __restrict__ x,
                  const unsigned int* __restrict__ batch_raw,
                  const float* __restrict__ H,
                  unsigned int* __restrict__ ws) {
    __shared__ float xs[BK * XS_STRIDE];
    __shared__ float hs[BK * HS_STRIDE];

    const int tid = threadIdx.x;
    const int blockBase = blockIdx.x * BM;
    const int ng = tid >> 3;   // 0..31 : node group (8 consecutive nodes)
    const int hg = tid & 7;    // 0..7  : hash group (hashes hg*8..+7 and 64+hg*8..+7)

    float acc[TN][TH];
    #pragma unroll
    for (int n = 0; n < TN; ++n)
        #pragma unroll
        for (int j = 0; j < TH; ++j)
            acc[n][j] = 0.0f;

    const int q  = tid & 3;    // k-quad within chunk
    const int rr = tid >> 2;   // 0..63

    for (int k0 = 0; k0 < KDIM; k0 += BK) {
        // ---- stage x tile: xs[k][node], 256 nodes x 16 k ----
        #pragma unroll
        for (int p = 0; p < 4; ++p) {
            const int nit = p * 64 + rr;
            const int gn  = blockBase + nit;
            float4 v = make_float4(0.f, 0.f, 0.f, 0.f);
            if (gn < M_NODES)
                v = *(const float4*)(x + (size_t)gn * KDIM + k0 + q * 4);
            xs[(q * 4 + 0) * XS_STRIDE + nit] = v.x;
            xs[(q * 4 + 1) * XS_STRIDE + nit] = v.y;
            xs[(q * 4 + 2) * XS_STRIDE + nit] = v.z;
            xs[(q * 4 + 3) * XS_STRIDE + nit] = v.w;
        }
        // ---- stage H tile: hs[k][hash], 128 hashes x 16 k ----
        #pragma unroll
        for (int p = 0; p < 2; ++p) {
            const int hh = p * 64 + rr;
            float4 v = *(const float4*)(H + (size_t)hh * KDIM + k0 + q * 4);
            hs[(q * 4 + 0) * HS_STRIDE + hh] = v.x;
            hs[(q * 4 + 1) * HS_STRIDE + hh] = v.y;
            hs[(q * 4 + 2) * HS_STRIDE + hh] = v.z;
            hs[(q * 4 + 3) * HS_STRIDE + hh] = v.w;
        }
        __syncthreads();

        // ---- compute: 8 nodes x 16 hashes per thread ----
        #pragma unroll
        for (int kk = 0; kk < BK; ++kk) {
            const float4 xa = *(const float4*)&xs[kk * XS_STRIDE + ng * 8];
            const float4 xb = *(const float4*)&xs[kk * XS_STRIDE + ng * 8 + 4];
            const float4 h0 = *(const float4*)&hs[kk * HS_STRIDE + hg * 8];
            const float4 h1 = *(const float4*)&hs[kk * HS_STRIDE + hg * 8 + 4];
            const float4 h2 = *(const float4*)&hs[kk * HS_STRIDE + 64 + hg * 8];
            const float4 h3 = *(const float4*)&hs[kk * HS_STRIDE + 64 + hg * 8 + 4];
            const float xv[TN] = {xa.x, xa.y, xa.z, xa.w, xb.x, xb.y, xb.z, xb.w};
            const float hv[TH] = {h0.x, h0.y, h0.z, h0.w, h1.x, h1.y, h1.z, h1.w,
                                  h2.x, h2.y, h2.z, h2.w, h3.x, h3.y, h3.z, h3.w};
            #pragma unroll
            for (int n = 0; n < TN; ++n)
                #pragma unroll
                for (int j = 0; j < TH; ++j)
                    acc[n][j] = fmaf(xv[n], hv[j], acc[n][j]);
        }
        __syncthreads();
    }

    // ---- segmented min reduction over this thread's 8 consecutive nodes ----
    // batch dtype sniffing: if int64, word[499999] is the high half of element
    // 249999 (value < 512 -> 0). If int32, it's batch[499999] ~= 511 != 0.
    const bool is64 = (batch_raw[499999] == 0u);
    const long long* b64 = (const long long*)batch_raw;
    const int*       b32 = (const int*)batch_raw;

    const int nbase = blockBase + ng * 8;
    int curseg = -1;
    float runmin[TH];
    #pragma unroll
    for (int j = 0; j < TH; ++j) runmin[j] = 0.0f;

    #pragma unroll
    for (int n = 0; n < TN; ++n) {
        const int gn = nbase + n;
        int seg = -1;
        if (gn < M_NODES) seg = is64 ? (int)b64[gn] : b32[gn];
        if (seg != curseg) {
            if (curseg >= 0) {
                #pragma unroll
                for (int j = 0; j < TH; ++j) {
                    const int h = (j < 8) ? (hg * 8 + j) : (64 + hg * 8 + (j - 8));
                    atomicMin(&ws[curseg * NHASH + h], enc_f(runmin[j]));
                }
            }
            curseg = seg;
            #pragma unroll
            for (int j = 0; j < TH; ++j) runmin[j] = acc[n][j];
        } else {
            #pragma unroll
            for (int j = 0; j < TH; ++j) runmin[j] = fminf(runmin[j], acc[n][j]);
        }
    }
    if (curseg >= 0) {
        #pragma unroll
        for (int j = 0; j < TH; ++j) {
            const int h = (j < 8) ? (hg * 8 + j) : (64 + hg * 8 + (j - 8));
            atomicMin(&ws[curseg * NHASH + h], enc_f(runmin[j]));
        }
    }
}

__global__ void minhash_finalize(const unsigned int* __restrict__ ws,
                                 float* __restrict__ out) {
    const int i = blockIdx.x * blockDim.x + threadIdx.x;
    if (i < NSEG * NHASH) {
        const unsigned int u = ws[i];
        float f;
        if (u == 0xFFFFFFFFu) {
            f = 0.0f;  // untouched sentinel == empty segment -> 0 (matches reference)
        } else {
            f = (u & 0x80000000u) ? __uint_as_float(u ^ 0x80000000u)
                                  : __uint_as_float(~u);
        }
        out[i] = f;
    }
}

extern "C" void kernel_launch(void* const* d_in, const int* in_sizes, int n_in,
                              void* d_out, int out_size, void* d_ws, size_t ws_size,
                              hipStream_t stream) {
    const float* x = (const float*)d_in[0];
    const unsigned int* batch = (const unsigned int*)d_in[1];
    const float* H = (const float*)d_in[3];
    unsigned int* ws = (unsigned int*)d_ws;

    // sentinel-init the atomic-min buffer (graph-capturable memset node)
    hipMemsetAsync(d_ws, 0xFF, NSEG * NHASH * sizeof(unsigned int), stream);

    const int grid = (M_NODES + BM - 1) / BM;  // 1954 blocks
    minhash_main<<<grid, 256, 0, stream>>>(x, batch, H, ws);
    minhash_finalize<<<(NSEG * NHASH + 255) / 256, 256, 0, stream>>>(ws, (float*)d_out);
}

// Round 2
// 856.923 us; speedup vs baseline: 1.3346x; 1.3346x over previous
//
#include <hip/hip_runtime.h>

// MinHashSketch: sketch[512,128] = segment_min(x[500000,256] @ H[128,256]^T), empty -> 0
// R1: SGPR-resident H (pre-transposed), 2-node x 32-hash thread tile (64 acc VGPRs),
//     pair-interleaved LDS x-tile (1 ds_read_b64 / 64 FMA), wave segmented-suffix-min
//     reduction so only run-start lanes issue atomics.

#define M_NODES 500000
#define KDIM    256
#define NHASH   128
#define NSEG    512

#define BM 128            // nodes per block (64 pairs, 1 pair per lane)
#define BK 32             // k-chunk
#define XSTR (BK + 1)     // float2 stride per pair-row: 33 -> <=2-way bank alias (free)

// Order-preserving float->uint encoding: uint-min == float-min
__device__ __forceinline__ unsigned int enc_f(float f) {
    unsigned int b = __float_as_uint(f);
    return (b & 0x80000000u) ? ~b : (b | 0x80000000u);
}

// One-time (per launch) transpose H[128][256] -> Ht[256][128] so a wave's 32 hash
// coefficients at fixed k are contiguous (s_load_dwordx16-able).
__global__ void ht_transpose(const float* __restrict__ H, float* __restrict__ Ht) {
    const int t = blockIdx.x * 256 + threadIdx.x;   // 32768 elements
    const int k = t >> 7;
    const int h = t & 127;
    Ht[t] = H[h * KDIM + k];
}

__global__ __launch_bounds__(256, 4)
void minhash_main(const float* __restrict__ x,
                  const unsigned int* __restrict__ batch_raw,
                  const float* __restrict__ Ht,
                  unsigned int* __restrict__ ws) {
    __shared__ float2 xsp[(BM / 2) * XSTR];   // 64 pairs x 33 float2 = 16.9 KB
    float* lds = (float*)xsp;

    const int tid  = threadIdx.x;
    const int lane = tid & 63;
    // wave-uniform hash-group base: wave w handles hashes [w*32, w*32+32)
    const int w32 = __builtin_amdgcn_readfirstlane(tid >> 6) * 32;
    const int blockBase = blockIdx.x * BM;

    float acc0[32], acc1[32];   // node 2*lane (even), 2*lane+1 (odd) x 32 hashes
    #pragma unroll
    for (int j = 0; j < 32; ++j) { acc0[j] = 0.0f; acc1[j] = 0.0f; }

    for (int k0 = 0; k0 < KDIM; k0 += BK) {
        // ---- stage x[blockBase..+127][k0..k0+31] into pair-interleaved LDS ----
        // 1024 float4s; idx -> node = idx>>3, f4 = idx&7 (8 lanes per node: 128 B
        // contiguous global segments). LDS float-offset for (node n, chunk-col k):
        // (n>>1)*2*XSTR + 2*k + (n&1)
        #pragma unroll
        for (int i = 0; i < 4; ++i) {
            const int idx = tid + 256 * i;
            const int n   = idx >> 3;
            const int f4  = idx & 7;
            const int gn  = blockBase + n;
            float4 v = make_float4(0.f, 0.f, 0.f, 0.f);
            if (gn < M_NODES)
                v = *(const float4*)(x + (size_t)gn * KDIM + k0 + f4 * 4);
            const int base = (n >> 1) * (2 * XSTR) + (n & 1) + f4 * 8;
            lds[base + 0] = v.x;
            lds[base + 2] = v.y;
            lds[base + 4] = v.z;
            lds[base + 6] = v.w;
        }
        __syncthreads();

        // ---- compute: per kk, 1 ds_read_b64 (2 nodes) + 32 uniform H values in
        // SGPRs + 64 v_fma_f32 with SGPR second source ----
        const float* hko = Ht + (size_t)k0 * NHASH + w32;
        #pragma unroll 4
        for (int kk = 0; kk < BK; ++kk) {
            const float2 xv = xsp[lane * XSTR + kk];
            const float* hk = hko + kk * NHASH;   // wave-uniform address
            #pragma unroll
            for (int j = 0; j < 32; ++j) {
                const float hv = hk[j];
                acc0[j] = fmaf(xv.x, hv, acc0[j]);
                acc1[j] = fmaf(xv.y, hv, acc1[j]);
            }
        }
        __syncthreads();
    }

    // ---- segment ids for this lane's node pair ----
    // batch dtype sniff: int64 -> word[499999] is high half of elem 249999 (==0);
    // int32 -> word[499999] == batch[499999] (sorted, ~511, nonzero).
    const bool is64 = (batch_raw[499999] == 0u);
    const long long* b64 = (const long long*)batch_raw;
    const int*       b32 = (const int*)batch_raw;

    const int gn0 = blockBase + 2 * lane;
    const int gn1 = gn0 + 1;
    int seg0 = -1, seg1 = -1;
    if (gn0 < M_NODES) seg0 = is64 ? (int)b64[gn0] : b32[gn0];
    if (gn1 < M_NODES) seg1 = is64 ? (int)b64[gn1] : b32[gn1];

    // ---- pair-level merge; if the pair straddles a boundary, flush node0 now ----
    float v[32];
    int seg;
    if (seg0 == seg1) {
        seg = seg0;
        #pragma unroll
        for (int j = 0; j < 32; ++j) v[j] = fminf(acc0[j], acc1[j]);
    } else {
        if (seg0 >= 0) {
            #pragma unroll
            for (int j = 0; j < 32; ++j)
                atomicMin(&ws[seg0 * NHASH + w32 + j], enc_f(acc0[j]));
        }
        seg = seg1;
        #pragma unroll
        for (int j = 0; j < 32; ++j) v[j] = acc1[j];
    }

    // ---- wave segmented suffix-min: lane l ends with min over its run's lanes ----
    #pragma unroll
    for (int d = 1; d < 64; d <<= 1) {
        const int  oseg = __shfl_down(seg, d, 64);
        const bool ok   = (lane + d < 64) && (oseg == seg);
        #pragma unroll
        for (int j = 0; j < 32; ++j) {
            const float ov = __shfl_down(v[j], d, 64);
            if (ok) v[j] = fminf(v[j], ov);
        }
    }

    // ---- only run-start lanes write atomics (~1 run per wave typical) ----
    const int pseg = __shfl_up(seg, 1, 64);
    if (seg >= 0 && (lane == 0 || pseg != seg)) {
        #pragma unroll
        for (int j = 0; j < 32; ++j)
            atomicMin(&ws[seg * NHASH + w32 + j], enc_f(v[j]));
    }
}

__global__ void minhash_finalize(const unsigned int* __restrict__ ws,
                                 float* __restrict__ out) {
    const int i = blockIdx.x * blockDim.x + threadIdx.x;
    if (i < NSEG * NHASH) {
        const unsigned int u = ws[i];
        out[i] = (u == 0xFFFFFFFFu)
                     ? 0.0f   // untouched sentinel == empty segment
                     : ((u & 0x80000000u) ? __uint_as_float(u ^ 0x80000000u)
                                          : __uint_as_float(~u));
    }
}

extern "C" void kernel_launch(void* const* d_in, const int* in_sizes, int n_in,
                              void* d_out, int out_size, void* d_ws, size_t ws_size,
                              hipStream_t stream) {
    const float* x = (const float*)d_in[0];
    const unsigned int* batch = (const unsigned int*)d_in[1];
    const float* H = (const float*)d_in[3];

    unsigned int* ws_atomic = (unsigned int*)d_ws;
    float* Ht = (float*)d_ws + NSEG * NHASH;   // 128 KB right after the 256 KB atomic area

    hipMemsetAsync(d_ws, 0xFF, NSEG * NHASH * sizeof(unsigned int), stream);
    ht_transpose<<<(KDIM * NHASH) / 256, 256, 0, stream>>>(H, Ht);

    const int grid = (M_NODES + BM - 1) / BM;  // 3907
    minhash_main<<<grid, 256, 0, stream>>>(x, batch, Ht, ws_atomic);
    minhash_finalize<<<(NSEG * NHASH + 255) / 256, 256, 0, stream>>>(ws_atomic, (float*)d_out);
}

// Round 3
// 731.600 us; speedup vs baseline: 1.5632x; 1.1713x over previous
//
#include <hip/hip_runtime.h>

// MinHashSketch: sketch[512,128] = segment_min(x[500000,256] @ H[128,256]^T), empty -> 0
// R2: split-bf16 MFMA GEMM (x=x1+x2, H=h1+h2, 4 cross-product mfma_f32_16x16x32_bf16),
//     fragment-linear LDS staging, acc->LDS epilogue + R1's wave segmented suffix-min.

#define M_NODES 500000
#define KDIM    256
#define NHASH   128
#define NSEG    512

#define BM     128
#define BK     32
#define NCHUNK (KDIM / BK)   // 8

typedef __attribute__((ext_vector_type(8))) short bf16x8;
typedef __attribute__((ext_vector_type(4))) float f32x4;

__device__ __forceinline__ unsigned short f2bf(float f) {
    unsigned int u = __float_as_uint(f);
    u += 0x7FFFu + ((u >> 16) & 1u);           // round-to-nearest-even
    return (unsigned short)(u >> 16);
}
__device__ __forceinline__ float bf2f(unsigned short s) {
    return __uint_as_float(((unsigned int)s) << 16);
}
// Order-preserving float->uint encoding: uint-min == float-min
__device__ __forceinline__ unsigned int enc_f(float f) {
    unsigned int b = __float_as_uint(f);
    return (b & 0x80000000u) ? ~b : (b | 0x80000000u);
}

// Pre-split H into hi/lo bf16 in MFMA-B-fragment-linear order:
// value B[k][n] = H[n][k]; idx = ((k>>5)*8 + (n>>4))*512 + (((k>>3)&3)*16 + (n&15))*8 + (k&7)
__global__ void hsplit(const float* __restrict__ H,
                       unsigned short* __restrict__ b1f,
                       unsigned short* __restrict__ b2f) {
    const int t = blockIdx.x * 256 + threadIdx.x;   // 32768 elements
    const int n = t >> 8;        // hash row
    const int k = t & 255;
    const float h = H[t];
    const unsigned short s1 = f2bf(h);
    const unsigned short s2 = f2bf(h - bf2f(s1));
    const int idx = ((k >> 5) * 8 + (n >> 4)) * 512 + (((k >> 3) & 3) * 16 + (n & 15)) * 8 + (k & 7);
    b1f[idx] = s1;
    b2f[idx] = s2;
}

// LDS A layout: tile T=row>>4 (0..7): T*576 + kg*144 + (row&15)*8 + j   (kg=k>>3 in chunk)
// (kg stride 144 shorts = 72 dwords == 8 mod 32 -> 2-way staging-write banks = free)
#define ATILE 576
#define AKG   144

__global__ __launch_bounds__(256, 3)
void minhash_main(const float* __restrict__ x,
                  const unsigned int* __restrict__ batch_raw,
                  const unsigned short* __restrict__ b1f,
                  const unsigned short* __restrict__ b2f,
                  unsigned int* __restrict__ ws) {
    __shared__ __align__(16) char smem[34816];
    unsigned short* a1 = (unsigned short*)smem;                 // 4608 shorts
    unsigned short* a2 = a1 + 4608;
    unsigned short* b1 = a1 + 9216;                             // 4096 shorts
    unsigned short* b2 = a1 + 13312;
    float* sc = (float*)smem;                                   // epilogue scratch 64x132 f32

    const int tid  = threadIdx.x;
    const int lane = tid & 63;
    const int w    = __builtin_amdgcn_readfirstlane(tid >> 6);  // wave 0..3
    const int quad = lane >> 4;
    const int c16  = lane & 15;
    const int rh   = w & 1;       // row-half (64 rows)
    const int ch   = w >> 1;      // col-half (64 cols)
    const long long blockBase = (long long)blockIdx.x * BM;

    f32x4 acc[4][4];
    #pragma unroll
    for (int rt = 0; rt < 4; ++rt)
        #pragma unroll
        for (int ct = 0; ct < 4; ++ct)
            acc[rt][ct] = (f32x4){0.f, 0.f, 0.f, 0.f};

    for (int chunk = 0; chunk < NCHUNK; ++chunk) {
        const int k0 = chunk * BK;

        // ---- stage B (straight fragment-linear copy, 8KB per split) ----
        {
            const float4* gb1 = (const float4*)(b1f + chunk * 4096);
            const float4* gb2 = (const float4*)(b2f + chunk * 4096);
            ((float4*)b1)[tid]       = gb1[tid];
            ((float4*)b1)[tid + 256] = gb1[tid + 256];
            ((float4*)b2)[tid]       = gb2[tid];
            ((float4*)b2)[tid + 256] = gb2[tid + 256];
        }
        // ---- stage A: load x fp32 coalesced, split to bf16 hi/lo, frag-linear LDS ----
        #pragma unroll
        for (int pass = 0; pass < 4; ++pass) {
            const int r  = (tid >> 3) + pass * 32;   // row in block
            const int f4 = tid & 7;                  // float4 slot in the 32-k chunk
            const long long gr = blockBase + r;
            float4 vv = make_float4(0.f, 0.f, 0.f, 0.f);
            if (gr < (long long)M_NODES)
                vv = *(const float4*)(x + gr * KDIM + k0 + f4 * 4);
            const unsigned short h1x = f2bf(vv.x), h1y = f2bf(vv.y),
                                 h1z = f2bf(vv.z), h1w = f2bf(vv.w);
            const unsigned short l1x = f2bf(vv.x - bf2f(h1x)), l1y = f2bf(vv.y - bf2f(h1y)),
                                 l1z = f2bf(vv.z - bf2f(h1z)), l1w = f2bf(vv.w - bf2f(h1w));
            const int base = (r >> 4) * ATILE + (f4 >> 1) * AKG + (r & 15) * 8 + (f4 & 1) * 4;
            uint2 p1, p2;
            p1.x = (unsigned)h1x | ((unsigned)h1y << 16);
            p1.y = (unsigned)h1z | ((unsigned)h1w << 16);
            p2.x = (unsigned)l1x | ((unsigned)l1y << 16);
            p2.y = (unsigned)l1z | ((unsigned)l1w << 16);
            *(uint2*)(a1 + base) = p1;
            *(uint2*)(a2 + base) = p2;
        }
        __syncthreads();

        // ---- MFMA: 4 row-tiles x 4 col-tiles x 4 split-products ----
        bf16x8 a1f[4], a2f[4];
        #pragma unroll
        for (int rt = 0; rt < 4; ++rt) {
            const int off = (rh * 4 + rt) * ATILE + quad * AKG + c16 * 8;
            a1f[rt] = *(const bf16x8*)(a1 + off);
            a2f[rt] = *(const bf16x8*)(a2 + off);
        }
        #pragma unroll
        for (int ct = 0; ct < 4; ++ct) {
            const int boff = ((ch * 4 + ct) * 64 + lane) * 8;
            const bf16x8 b1v = *(const bf16x8*)(b1 + boff);
            const bf16x8 b2v = *(const bf16x8*)(b2 + boff);
            #pragma unroll
            for (int rt = 0; rt < 4; ++rt) {
                acc[rt][ct] = __builtin_amdgcn_mfma_f32_16x16x32_bf16(a1f[rt], b1v, acc[rt][ct], 0, 0, 0);
                acc[rt][ct] = __builtin_amdgcn_mfma_f32_16x16x32_bf16(a2f[rt], b1v, acc[rt][ct], 0, 0, 0);
                acc[rt][ct] = __builtin_amdgcn_mfma_f32_16x16x32_bf16(a1f[rt], b2v, acc[rt][ct], 0, 0, 0);
                acc[rt][ct] = __builtin_amdgcn_mfma_f32_16x16x32_bf16(a2f[rt], b2v, acc[rt][ct], 0, 0, 0);
            }
        }
        __syncthreads();
    }

    // ---- epilogue: segment ids for this lane's node pair (reduction mapping) ----
    // batch dtype sniff: int64 -> word[499999] is high half of elem 249999 (==0);
    // int32 -> word[499999] == batch[499999] (sorted, ~511, nonzero).
    const bool is64 = (batch_raw[499999] == 0u);
    const long long* bb64 = (const long long*)batch_raw;
    const int*       bb32 = (const int*)batch_raw;

    const int p = lane;                // node-pair index: nodes 2p, 2p+1 (block-rel)
    const int cg = w;                  // col-group within the 64-col half
    const long long gn0 = blockBase + 2 * p;
    const long long gn1 = gn0 + 1;
    int seg0 = -1, seg1 = -1;
    if (gn0 < (long long)M_NODES) seg0 = is64 ? (int)bb64[gn0] : bb32[gn0];
    if (gn1 < (long long)M_NODES) seg1 = is64 ? (int)bb64[gn1] : bb32[gn1];

    for (int h = 0; h < 2; ++h) {
        // waves holding this col-half write acc to sc[col'][node], stride 132
        if (ch == h) {
            #pragma unroll
            for (int ct = 0; ct < 4; ++ct) {
                #pragma unroll
                for (int rt = 0; rt < 4; ++rt) {
                    const int node = rh * 64 + rt * 16 + quad * 4;
                    const int colp = ct * 16 + c16;
                    *(f32x4*)(sc + colp * 132 + node) = acc[rt][ct];
                }
            }
        }
        __syncthreads();

        // pair-merge + wave segmented suffix-min over 64 node-pairs
        float v[16];
        int seg;
        if (seg0 == seg1) {
            seg = seg0;
            #pragma unroll
            for (int j = 0; j < 16; ++j) {
                const float2 nv = *(const float2*)(sc + (cg * 16 + j) * 132 + 2 * p);
                v[j] = fminf(nv.x, nv.y);
            }
        } else {
            seg = seg1;
            #pragma unroll
            for (int j = 0; j < 16; ++j) {
                const float2 nv = *(const float2*)(sc + (cg * 16 + j) * 132 + 2 * p);
                if (seg0 >= 0)
                    atomicMin(&ws[seg0 * NHASH + h * 64 + cg * 16 + j], enc_f(nv.x));
                v[j] = nv.y;
            }
        }
        #pragma unroll
        for (int d = 1; d < 64; d <<= 1) {
            const int  oseg = __shfl_down(seg, d, 64);
            const bool ok   = (lane + d < 64) && (oseg == seg);
            #pragma unroll
            for (int j = 0; j < 16; ++j) {
                const float ov = __shfl_down(v[j], d, 64);
                if (ok) v[j] = fminf(v[j], ov);
            }
        }
        const int pseg = __shfl_up(seg, 1, 64);
        if (seg >= 0 && (lane == 0 || pseg != seg)) {
            #pragma unroll
            for (int j = 0; j < 16; ++j)
                atomicMin(&ws[seg * NHASH + h * 64 + cg * 16 + j], enc_f(v[j]));
        }
        __syncthreads();
    }
}

__global__ void minhash_finalize(const unsigned int* __restrict__ ws,
                                 float* __restrict__ out) {
    const int i = blockIdx.x * blockDim.x + threadIdx.x;
    if (i < NSEG * NHASH) {
        const unsigned int u = ws[i];
        out[i] = (u == 0xFFFFFFFFu)
                     ? 0.0f   // untouched sentinel == empty segment
                     : ((u & 0x80000000u) ? __uint_as_float(u ^ 0x80000000u)
                                          : __uint_as_float(~u));
    }
}

extern "C" void kernel_launch(void* const* d_in, const int* in_sizes, int n_in,
                              void* d_out, int out_size, void* d_ws, size_t ws_size,
                              hipStream_t stream) {
    const float* x = (const float*)d_in[0];
    const unsigned int* batch = (const unsigned int*)d_in[1];
    const float* H = (const float*)d_in[3];

    unsigned int*   ws  = (unsigned int*)d_ws;
    unsigned short* b1f = (unsigned short*)((char*)d_ws + 256 * 1024);
    unsigned short* b2f = (unsigned short*)((char*)d_ws + 320 * 1024);

    hipMemsetAsync(d_ws, 0xFF, NSEG * NHASH * sizeof(unsigned int), stream);
    hsplit<<<(KDIM * NHASH) / 256, 256, 0, stream>>>(H, b1f, b2f);

    const int grid = (M_NODES + BM - 1) / BM;  // 3907
    minhash_main<<<grid, 256, 0, stream>>>(x, batch, b1f, b2f, ws);
    minhash_finalize<<<(NSEG * NHASH + 255) / 256, 256, 0, stream>>>(ws, (float*)d_out);
}